// Round 8
// baseline (24.400 us; speedup 1.0000x reference)
//
#include <hip/hip_runtime.h>

#define SEQ 256
#define NENV 64
#define NGROUPS 12
#define GDIM 128
#define ROWS (SEQ * NENV)           // 16384
#define TPB 1024                    // 16 waves per block
#define WPB 16                      // waves (= rows) per block
#define NBLOCKS (ROWS / WPB)        // 1024

typedef int v2i_t __attribute__((ext_vector_type(2)));

// Butterfly add via DPP (VALU pipe, not LDS). Valid ctrls only.
template <int CTRL>
__device__ __forceinline__ float dpp_add(float x) {
    const int yi = __builtin_amdgcn_update_dpp(
        0, __float_as_int(x), CTRL, 0xF, 0xF, true);
    return x + __int_as_float(yi);
}

// xor16 within each 32-lane half via ds_swizzle (bitmode: xor=16, and=0x1F).
__device__ __forceinline__ float swz_add_xor16(float x) {
    const int yi = __builtin_amdgcn_ds_swizzle(__float_as_int(x), 0x401F);
    return x + __int_as_float(yi);
}

// permlane32_swap(x,x): returns {lo-half value, hi-half value} at this lane's
// position-within-half — VALU pipe, both halves visible to every lane.
__device__ __forceinline__ float2 both_halves(float x) {
    const int xi = __float_as_int(x);
    v2i_t pr = __builtin_amdgcn_permlane32_swap(xi, xi, false, false);
    return make_float2(__int_as_float(pr[0]), __int_as_float(pr[1]));
}

// Single fused kernel (R7 structure; row body reduction moved off the DS pipe).
__global__ __launch_bounds__(TPB, 8)
void group_attn_fused(const float* __restrict__ ge,     // (ROWS, 12, 128)
                      const float* __restrict__ Wg,     // (128, 128)
                      const float* __restrict__ Wa,     // (256, 1)
                      float* __restrict__ out_weighted, // (ROWS, 128)
                      float* __restrict__ out_weights)  // (ROWS, 12)
{
    __shared__ float p1[4096];      // quad partials (16 KB)
    __shared__ float p2[8][128];    // stage-2 partials (4 KB)
    __shared__ float v_lds[GDIM];

    const int tid  = threadIdx.x;
    const int wave = tid >> 6;
    const int lane = tid & 63;
    const int row  = blockIdx.x * WPB + wave;
    const int half = lane >> 5;     // 0: even groups, 1: odd groups
    const int l32  = lane & 31;     // dims [l32*4, l32*4+3]

    // ---- Phase A: issue ge loads first; latency hides under the fold.
    const float* base = ge + (size_t)row * (NGROUPS * GDIM) + lane * 4;
    float4 g[6];
#pragma unroll
    for (int t = 0; t < 6; ++t)
        g[t] = *reinterpret_cast<const float4*>(base + t * 256);

    // ---- Phase B: fold prologue (coalesced), v = Wg @ Wa[128:256].
    {
        const float4* wg4 = reinterpret_cast<const float4*>(Wg);     // 4096 quads
        const float4  waf = reinterpret_cast<const float4*>(Wa + 128)[tid & 31];
#pragma unroll
        for (int k = 0; k < 4; ++k) {
            const int q = tid + TPB * k;
            const float4 f = wg4[q];
            p1[q] = f.x * waf.x + f.y * waf.y + f.z * waf.z + f.w * waf.w;
        }
    }
    __syncthreads();
    {
        const int d = tid >> 3, oct = tid & 7;
        const float4 r = *reinterpret_cast<const float4*>(&p1[d * 32 + oct * 4]);
        p2[oct][d] = r.x + r.y + r.z + r.w;
    }
    __syncthreads();
    if (tid < GDIM) {
        float s = 0.0f;
#pragma unroll
        for (int o = 0; o < 8; ++o) s += p2[o][tid];
        v_lds[tid] = s;
    }
    __syncthreads();

    const float4 vf = *reinterpret_cast<const float4*>(&v_lds[l32 * 4]);

    // ---- Phase C: row body — all-lane scores with DPP/permlane reduction.
    float sc[12];
#pragma unroll
    for (int t = 0; t < 6; ++t) {
        float p = g[t].x * vf.x + g[t].y * vf.y + g[t].z * vf.z + g[t].w * vf.w;
        p = dpp_add<0xB1>(p);    // quad_perm [1,0,3,2]  : + lane^1
        p = dpp_add<0x4E>(p);    // quad_perm [2,3,0,1]  : + lane^2
        p = dpp_add<0x141>(p);   // row_half_mirror (xor7; quad-uniform => xor4)
        p = dpp_add<0x140>(p);   // row_mirror (xor15; octet-uniform => xor8)
        p = swz_add_xor16(p);    // + lane^16 -> uniform within each 32-half
        const float2 b = both_halves(p);
        sc[2 * t]     = b.x;     // even-group score, in ALL lanes
        sc[2 * t + 1] = b.y;     // odd-group score, in ALL lanes
    }

    // Softmax over 12 scores — pure register math, no cross-lane ops.
    float m = sc[0];
#pragma unroll
    for (int i = 1; i < NGROUPS; ++i) m = fmaxf(m, sc[i]);
    float w[12];
    float sum = 0.0f;
#pragma unroll
    for (int i = 0; i < NGROUPS; ++i) {
        w[i] = __expf(sc[i] - m);
        sum += w[i];
    }
    const float inv = 1.0f / sum;
#pragma unroll
    for (int i = 0; i < NGROUPS; ++i) w[i] *= inv;

    // Weighted sum of group embeddings (registers), combine halves via
    // permlane32_swap (VALU): total = lo + hi at my dim position.
    float4 acc = make_float4(0.f, 0.f, 0.f, 0.f);
#pragma unroll
    for (int t = 0; t < 6; ++t) {
        const float wt = w[2 * t + half];
        acc.x += wt * g[t].x;
        acc.y += wt * g[t].y;
        acc.z += wt * g[t].z;
        acc.w += wt * g[t].w;
    }
    const float2 cx = both_halves(acc.x);
    const float2 cy = both_halves(acc.y);
    const float2 cz = both_halves(acc.z);
    const float2 cw = both_halves(acc.w);

    if (lane < 32) {
        const float4 o = make_float4(cx.x + cx.y, cy.x + cy.y,
                                     cz.x + cz.y, cw.x + cw.y);
        *reinterpret_cast<float4*>(out_weighted + (size_t)row * GDIM + l32 * 4) = o;
    } else if (lane < 32 + NGROUPS) {
        out_weights[(size_t)row * NGROUPS + (lane - 32)] = w[lane - 32];
    }
}

extern "C" void kernel_launch(void* const* d_in, const int* in_sizes, int n_in,
                              void* d_out, int out_size, void* d_ws, size_t ws_size,
                              hipStream_t stream) {
    // Inputs: 0 robot_states (unused) 1 group_embeddings 2 Wr (unused)
    // 3 br (unused) 4 Wg 5 bg (unused) 6 Wa 7 ba (unused)
    const float* ge = (const float*)d_in[1];
    const float* Wg = (const float*)d_in[4];
    const float* Wa = (const float*)d_in[6];

    float* out_weighted = (float*)d_out;                       // ROWS*128
    float* out_weights  = out_weighted + (size_t)ROWS * GDIM;  // ROWS*12

    group_attn_fused<<<NBLOCKS, TPB, 0, stream>>>(
        ge, Wg, Wa, out_weighted, out_weights);
}

// Round 9
// 23.624 us; speedup vs baseline: 1.0328x; 1.0328x over previous
//
#include <hip/hip_runtime.h>

#define SEQ 256
#define NENV 64
#define NGROUPS 12
#define GDIM 128
#define ROWS (SEQ * NENV)           // 16384
#define TPB 512                     // 8 waves per block
#define WPB 8                       // waves (= rows) per block
#define NBLOCKS (ROWS / WPB)        // 2048

// Single fused kernel (R7 structure, 512-thread blocks).
// Phase A (per wave): issue the 6 ge row loads (independent of v).
// Phase B (per block): coalesced fold v = Wg @ Wa[128:256] into LDS.
// Phase C (per wave): R7-verbatim row body (measured-fastest variant).
__global__ __launch_bounds__(TPB, 8)
void group_attn_fused(const float* __restrict__ ge,     // (ROWS, 12, 128)
                      const float* __restrict__ Wg,     // (128, 128)
                      const float* __restrict__ Wa,     // (256, 1)
                      float* __restrict__ out_weighted, // (ROWS, 128)
                      float* __restrict__ out_weights)  // (ROWS, 12)
{
    __shared__ float p1[4096];      // quad partials (16 KB)
    __shared__ float p2[4][128];    // stage-2 partials (2 KB)
    __shared__ float v_lds[GDIM];

    const int tid  = threadIdx.x;
    const int wave = tid >> 6;
    const int lane = tid & 63;
    const int row  = blockIdx.x * WPB + wave;
    const int half = lane >> 5;     // 0: even groups, 1: odd groups
    const int l32  = lane & 31;     // dims [l32*4, l32*4+3]

    // ---- Phase A: issue ge loads first; latency hides under the fold.
    const float* base = ge + (size_t)row * (NGROUPS * GDIM) + lane * 4;
    float4 g[6];
#pragma unroll
    for (int t = 0; t < 6; ++t)
        g[t] = *reinterpret_cast<const float4*>(base + t * 256);

    // ---- Phase B: fold prologue (coalesced), v = Wg @ Wa[128:256].
    // Thread tid handles quads {tid + 512k}, k=0..7; quad q covers columns
    // 4*(q%32) of row q/32, and q%32 == tid%32 (512 % 32 == 0).
    {
        const float4* wg4 = reinterpret_cast<const float4*>(Wg);     // 4096 quads
        const float4  waf = reinterpret_cast<const float4*>(Wa + 128)[tid & 31];
#pragma unroll
        for (int k = 0; k < 8; ++k) {
            const int q = tid + TPB * k;
            const float4 f = wg4[q];
            p1[q] = f.x * waf.x + f.y * waf.y + f.z * waf.z + f.w * waf.w;
        }
    }
    __syncthreads();
    {
        // 4 threads per output dim d: each sums 8 quad-partials (2 b128 reads).
        const int d = tid >> 2, sub = tid & 3;
        const float4 r0 = *reinterpret_cast<const float4*>(&p1[d * 32 + sub * 8]);
        const float4 r1 = *reinterpret_cast<const float4*>(&p1[d * 32 + sub * 8 + 4]);
        p2[sub][d] = (r0.x + r0.y + r0.z + r0.w) + (r1.x + r1.y + r1.z + r1.w);
    }
    __syncthreads();
    if (tid < GDIM) {
        v_lds[tid] = (p2[0][tid] + p2[1][tid]) + (p2[2][tid] + p2[3][tid]);
    }
    __syncthreads();

    const float4 vf = *reinterpret_cast<const float4*>(&v_lds[l32 * 4]);

    // ---- Phase C: R7-verbatim row body (shuffle butterfly).
    float sc[12];
#pragma unroll
    for (int t = 0; t < 6; ++t) {
        float p = g[t].x * vf.x + g[t].y * vf.y + g[t].z * vf.z + g[t].w * vf.w;
        p += __shfl_xor(p, 1);
        p += __shfl_xor(p, 2);
        p += __shfl_xor(p, 4);
        p += __shfl_xor(p, 8);
        p += __shfl_xor(p, 16);
        float q = __shfl_xor(p, 32);
        sc[2 * t]     = half ? q : p;
        sc[2 * t + 1] = half ? p : q;
    }

    float m = sc[0];
#pragma unroll
    for (int i = 1; i < NGROUPS; ++i) m = fmaxf(m, sc[i]);
    float w[12];
    float sum = 0.0f;
#pragma unroll
    for (int i = 0; i < NGROUPS; ++i) {
        w[i] = __expf(sc[i] - m);
        sum += w[i];
    }
    const float inv = 1.0f / sum;
#pragma unroll
    for (int i = 0; i < NGROUPS; ++i) w[i] *= inv;

    float4 acc = make_float4(0.f, 0.f, 0.f, 0.f);
#pragma unroll
    for (int t = 0; t < 6; ++t) {
        const float wt = w[2 * t + half];
        acc.x += wt * g[t].x;
        acc.y += wt * g[t].y;
        acc.z += wt * g[t].z;
        acc.w += wt * g[t].w;
    }
    acc.x += __shfl_xor(acc.x, 32);
    acc.y += __shfl_xor(acc.y, 32);
    acc.z += __shfl_xor(acc.z, 32);
    acc.w += __shfl_xor(acc.w, 32);

    if (lane < 32) {
        *reinterpret_cast<float4*>(out_weighted + (size_t)row * GDIM + l32 * 4) = acc;
    } else if (lane < 32 + NGROUPS) {
        out_weights[(size_t)row * NGROUPS + (lane - 32)] = w[lane - 32];
    }
}

extern "C" void kernel_launch(void* const* d_in, const int* in_sizes, int n_in,
                              void* d_out, int out_size, void* d_ws, size_t ws_size,
                              hipStream_t stream) {
    // Inputs: 0 robot_states (unused) 1 group_embeddings 2 Wr (unused)
    // 3 br (unused) 4 Wg 5 bg (unused) 6 Wa 7 ba (unused)
    const float* ge = (const float*)d_in[1];
    const float* Wg = (const float*)d_in[4];
    const float* Wa = (const float*)d_in[6];

    float* out_weighted = (float*)d_out;                       // ROWS*128
    float* out_weights  = out_weighted + (size_t)ROWS * GDIM;  // ROWS*12

    group_attn_fused<<<NBLOCKS, TPB, 0, stream>>>(
        ge, Wg, Wa, out_weighted, out_weights);
}